// Round 3
// baseline (103.898 us; speedup 1.0000x reference)
//
#include <hip/hip_runtime.h>
#include <math.h>

#define E_DIM 2048

typedef __attribute__((ext_vector_type(8))) short short8;
typedef __attribute__((ext_vector_type(4))) float floatx4;

__device__ __forceinline__ float siluf(float v) { return v / (1.f + expf(-v)); }

// f32 -> bf16 bits, round-to-nearest-even
__device__ __forceinline__ short f2bf(float f) {
    unsigned u = __float_as_uint(f);
    u += 0x7fffu + ((u >> 16) & 1u);
    return (short)(u >> 16);
}

// ---------------- Fused: LayerNorm (blocks 0..127) + accumulator zeroing (blocks 128..) ----------------
__global__ __launch_bounds__(256) void ln_zero_kernel(const float* __restrict__ x,
                                                      const float* __restrict__ g,
                                                      const float* __restrict__ be,
                                                      const float* __restrict__ c,
                                                      short* __restrict__ h_bf,
                                                      short* __restrict__ c_bf,
                                                      float4* __restrict__ zbase,
                                                      int zTotal) {
    int tid = threadIdx.x;
    if (blockIdx.x < 128) {
        int b = blockIdx.x;
        __shared__ float sdata[256];
        const float* xr = x + b * 1024;
        float v[4];
        float s = 0.f;
#pragma unroll
        for (int i = 0; i < 4; ++i) { v[i] = xr[tid + i * 256]; s += v[i]; }
        sdata[tid] = s; __syncthreads();
        for (int st = 128; st > 0; st >>= 1) { if (tid < st) sdata[tid] += sdata[tid + st]; __syncthreads(); }
        float mu = sdata[0] * (1.f / 1024.f);
        __syncthreads();
        float s2 = 0.f;
#pragma unroll
        for (int i = 0; i < 4; ++i) { float d = v[i] - mu; s2 += d * d; }
        sdata[tid] = s2; __syncthreads();
        for (int st = 128; st > 0; st >>= 1) { if (tid < st) sdata[tid] += sdata[tid + st]; __syncthreads(); }
        float var = sdata[0] * (1.f / 1024.f);
        float inv = rsqrtf(var + 1e-5f);
        short* hr = h_bf + b * 1024;
#pragma unroll
        for (int i = 0; i < 4; ++i) {
            int j = tid + i * 256;
            hr[j] = f2bf((v[i] - mu) * inv * g[j] + be[j]);
        }
        const float* cr = c + b * 512;
        short* cbr = c_bf + b * 512;
        for (int j = tid; j < 512; j += 256) cbr[j] = f2bf(cr[j]);
    } else {
        // zero accumulators: each thread writes 8 float4s, grid-stride
        int base = (blockIdx.x - 128) * 2048 + tid;  // in float4 units
        int stride = (gridDim.x - 128) * 2048;
        for (int idx = base; idx < zTotal; idx += stride) {
#pragma unroll
            for (int i = 0; i < 8; ++i) {
                int k = idx + i * 256;
                if (k < zTotal) zbase[k] = (float4){0.f, 0.f, 0.f, 0.f};
            }
        }
    }
}

// ---------------- A-fragment loader with fused elementwise transforms ----------------
// MODE 0: A is bf16 (short*), passthrough
// MODE 1: A = xz_acc f32; u = silu(A*cw3[j]+cb[j])          (aux0=convw+3*E, aux1=convb)
// MODE 2: A = f32, plain convert                             (d_r from xdbl)
// MODE 3: A = mo_acc f32; mamba = A + b_out[j] + x[r][j]     (aux0=b_out, aux1=x)
// MODE 4: A = zd_acc f32; z = gelu(A+b_d[j])*g + b  (FiLM)   (aux0=b_d, aux1=gb_acc, aux2=b_f)
template<int MODE>
__device__ __forceinline__ short8 load_a_frag(const void* __restrict__ A, int lda, int r, int j0,
                                              const float* __restrict__ aux0,
                                              const float* __restrict__ aux1,
                                              const float* __restrict__ aux2) {
    if constexpr (MODE == 0) {
        return *(const short8*)((const short*)A + (size_t)r * lda + j0);
    } else {
        const float* p = (const float*)A + (size_t)r * lda + j0;
        float v[8];
        if constexpr (MODE == 1) {
#pragma unroll
            for (int i = 0; i < 8; ++i) v[i] = siluf(p[i] * aux0[j0 + i] + aux1[j0 + i]);
        } else if constexpr (MODE == 2) {
#pragma unroll
            for (int i = 0; i < 8; ++i) v[i] = p[i];
        } else if constexpr (MODE == 3) {
#pragma unroll
            for (int i = 0; i < 8; ++i) v[i] = p[i] + aux0[j0 + i] + aux1[(size_t)r * lda + j0 + i];
        } else {  // MODE 4
#pragma unroll
            for (int i = 0; i < 8; ++i) {
                float t = p[i] + aux0[j0 + i];
                float zg = 0.5f * t * (1.f + erff(t * 0.70710678118654752f));
                float gq = aux1[(size_t)r * 1024 + j0 + i] + aux2[j0 + i];
                float bb = aux1[(size_t)r * 1024 + 512 + j0 + i] + aux2[512 + j0 + i];
                v[i] = zg * gq + bb;
            }
        }
        short8 s;
#pragma unroll
        for (int i = 0; i < 8; ++i) s[i] = f2bf(v[i]);
        return s;
    }
}

// ---------------- MFMA split-K GEMM: C += transform(A)(128 x K) * bf16(B_f32(K x N)) ----------------
// Block = 4 waves; wave w owns rows [w*32, w*32+32); block owns cols [bx*64, bx*64+64).
template<int MODE>
__global__ __launch_bounds__(256) void gemm_mfma(const void* __restrict__ A, int lda,
                                                 const float* __restrict__ aux0,
                                                 const float* __restrict__ aux1,
                                                 const float* __restrict__ aux2,
                                                 const float* __restrict__ B, int ldb,
                                                 float* __restrict__ C, int ldc,
                                                 int kChunk) {
    const int tid = threadIdx.x;
    const int w = tid >> 6;
    const int l = tid & 63;
    const int lane15 = l & 15;
    const int lgrp = l >> 4;
    const int n0 = blockIdx.x * 64;
    const int k0 = blockIdx.z * kChunk;

    const int r0 = w * 32 + lane15;
    const float* Bp = B + (size_t)(k0 + lgrp * 8) * ldb + n0 + lane15;

    floatx4 acc[2][4];
#pragma unroll
    for (int i = 0; i < 2; ++i)
#pragma unroll
        for (int j = 0; j < 4; ++j) acc[i][j] = (floatx4)0.f;

    for (int ks = 0; ks < kChunk; ks += 32) {
        int j0 = k0 + ks + lgrp * 8;
        short8 a0 = load_a_frag<MODE>(A, lda, r0, j0, aux0, aux1, aux2);
        short8 a1 = load_a_frag<MODE>(A, lda, r0 + 16, j0, aux0, aux1, aux2);
        float bv[4][8];
#pragma unroll
        for (int i = 0; i < 8; ++i) {
            const float* Br = Bp + i * ldb;
#pragma unroll
            for (int nt = 0; nt < 4; ++nt) bv[nt][i] = Br[nt * 16];
        }
        Bp += 32 * (size_t)ldb;
        short8 vb[4];
#pragma unroll
        for (int nt = 0; nt < 4; ++nt)
#pragma unroll
            for (int i = 0; i < 8; ++i) vb[nt][i] = f2bf(bv[nt][i]);
#pragma unroll
        for (int nt = 0; nt < 4; ++nt) {
            acc[0][nt] = __builtin_amdgcn_mfma_f32_16x16x32_bf16(a0, vb[nt], acc[0][nt], 0, 0, 0);
            acc[1][nt] = __builtin_amdgcn_mfma_f32_16x16x32_bf16(a1, vb[nt], acc[1][nt], 0, 0, 0);
        }
    }
    const int rbase = w * 32 + lgrp * 4;
#pragma unroll
    for (int mf = 0; mf < 2; ++mf)
#pragma unroll
        for (int nt = 0; nt < 4; ++nt)
#pragma unroll
            for (int r = 0; r < 4; ++r)
                atomicAdd(&C[(rbase + mf * 16 + r) * ldc + n0 + nt * 16 + lane15], acc[mf][nt][r]);
}

// ---------------- e3: per-batch-row: svec dot + y = u*(softplus(.)*svec + D)*sres -> bf16 ----------------
__global__ __launch_bounds__(256) void e3_kernel(const float* __restrict__ dacc,
                                                 const float* __restrict__ b_dt,
                                                 const float* __restrict__ xz,
                                                 const float* __restrict__ convw3,
                                                 const float* __restrict__ convb,
                                                 const float* __restrict__ xdbl,
                                                 const float* __restrict__ Dv,
                                                 short* __restrict__ y_bf) {
    int b = blockIdx.x;
    int tid = threadIdx.x;
    __shared__ float sdata[256];
    const float* row = xdbl + b * 1536;
    float s = 0.f;
    for (int n = tid; n < 512; n += 256) s += row[512 + n] * row[1024 + n];
    sdata[tid] = s; __syncthreads();
    for (int st = 128; st > 0; st >>= 1) { if (tid < st) sdata[tid] += sdata[tid + st]; __syncthreads(); }
    float svec = sdata[0];
    const float* xzr = xz + b * 4096;
    const float* dar = dacc + b * 2048;
    short* yr = y_bf + b * 2048;
#pragma unroll
    for (int ii = 0; ii < 8; ++ii) {
        int j = tid + ii * 256;
        float t = dar[j] + b_dt[j];
        float delta = fmaxf(t, 0.f) + log1pf(expf(-fabsf(t)));  // stable softplus
        float u = siluf(xzr[j] * convw3[j] + convb[j]);
        float sr = siluf(xzr[2048 + j]);
        yr[j] = f2bf(u * (delta * svec + Dv[j]) * sr);
    }
}

// ---------------- e6: out = out_acc + b_o ----------------
__global__ __launch_bounds__(256) void e6_kernel(const float* __restrict__ oa,
                                                 const float* __restrict__ b_o,
                                                 float* __restrict__ out) {
    int idx = blockIdx.x * 256 + threadIdx.x;  // 128*1024
    int j = idx & 1023;
    out[idx] = oa[idx] + b_o[j];
}

extern "C" void kernel_launch(void* const* d_in, const int* in_sizes, int n_in,
                              void* d_out, int out_size, void* d_ws, size_t ws_size,
                              hipStream_t stream) {
    (void)in_sizes; (void)n_in; (void)out_size; (void)ws_size;
    const float* x     = (const float*)d_in[0];
    const float* c     = (const float*)d_in[1];
    const float* ln_g  = (const float*)d_in[2];
    const float* ln_b  = (const float*)d_in[3];
    const float* W_in  = (const float*)d_in[4];
    const float* convw = (const float*)d_in[5];
    const float* convb = (const float*)d_in[6];
    const float* W_x   = (const float*)d_in[7];
    const float* W_dt  = (const float*)d_in[8];
    const float* b_dt  = (const float*)d_in[9];
    // d_in[10] = A_log: provably unused (scan length 1 from h0 = 0)
    const float* Dv    = (const float*)d_in[11];
    const float* W_out = (const float*)d_in[12];
    const float* b_out = (const float*)d_in[13];
    const float* W_d   = (const float*)d_in[14];
    const float* b_d   = (const float*)d_in[15];
    const float* W_f   = (const float*)d_in[16];
    const float* b_f   = (const float*)d_in[17];
    const float* W_o   = (const float*)d_in[18];
    const float* b_o   = (const float*)d_in[19];
    float* out = (float*)d_out;

    char* ws = (char*)d_ws;
    size_t off = 0;
    auto allocf = [&](size_t nElem) { float* p = (float*)(ws + off); off += nElem * sizeof(float); return p; };
    auto allocs = [&](size_t nElem) { short* p = (short*)(ws + off); off += nElem * sizeof(short); return p; };
    // accumulator region (zeroed each launch by ln_zero_kernel)
    float* xz_acc   = allocf(128 * 4096);
    float* xdbl_acc = allocf(128 * 1536);
    float* dacc     = allocf(128 * 2048);
    float* mo_acc   = allocf(128 * 1024);
    float* zd_acc   = allocf(128 * 512);
    float* gb_acc   = allocf(128 * 1024);
    float* out_acc  = allocf(128 * 1024);
    size_t accBytes = off;
    int zTotal = (int)(accBytes / 16);  // float4 count (all sizes 16B-multiples)
    // plain scratch
    short* h_bf   = allocs(128 * 1024);
    short* c_bf   = allocs(128 * 512);
    short* y_bf   = allocs(128 * 2048);

    // 1) fused LN + zero  (128 LN blocks + 176 zero blocks)
    ln_zero_kernel<<<128 + 176, 256, 0, stream>>>(x, ln_g, ln_b, c, h_bf, c_bf,
                                                  (float4*)d_ws, zTotal);
    // 2) G1: h(128x1024) @ W_in(1024x4096) -> xz_acc   [S=4]
    gemm_mfma<0><<<dim3(64, 1, 4), 256, 0, stream>>>(h_bf, 1024, nullptr, nullptr, nullptr,
                                                     W_in, 4096, xz_acc, 4096, 256);
    // 3) G6: c(128x512) @ W_f(512x1024) -> gb_acc   [S=8]
    gemm_mfma<0><<<dim3(16, 1, 8), 256, 0, stream>>>(c_bf, 512, nullptr, nullptr, nullptr,
                                                     W_f, 1024, gb_acc, 1024, 64);
    // 4) G2: silu(conv(xz)) (128x2048) @ W_x(2048x1536) -> xdbl_acc   [S=8]
    gemm_mfma<1><<<dim3(24, 1, 8), 256, 0, stream>>>(xz_acc, 4096, convw + 3 * E_DIM, convb, nullptr,
                                                     W_x, 1536, xdbl_acc, 1536, 256);
    // 5) G3: d_r(128x512) @ W_dt(512x2048) -> dacc   [S=8]
    gemm_mfma<2><<<dim3(32, 1, 8), 256, 0, stream>>>(xdbl_acc, 1536, nullptr, nullptr, nullptr,
                                                     W_dt, 2048, dacc, 2048, 64);
    // 6) e3: svec + y  (per batch row)
    e3_kernel<<<128, 256, 0, stream>>>(dacc, b_dt, xz_acc, convw + 3 * E_DIM, convb,
                                       xdbl_acc, Dv, y_bf);
    // 7) G4: y(128x2048) @ W_out(2048x1024) -> mo_acc   [S=8]
    gemm_mfma<0><<<dim3(16, 1, 8), 256, 0, stream>>>(y_bf, 2048, nullptr, nullptr, nullptr,
                                                     W_out, 1024, mo_acc, 1024, 256);
    // 8) G5: (mo + b_out + x)(128x1024) @ W_d(1024x512) -> zd_acc   [S=16]
    gemm_mfma<3><<<dim3(8, 1, 16), 256, 0, stream>>>(mo_acc, 1024, b_out, x, nullptr,
                                                     W_d, 512, zd_acc, 512, 64);
    // 9) G7: FiLM(gelu(zd+b_d))(128x512) @ W_o(512x1024) -> out_acc   [S=8]
    gemm_mfma<4><<<dim3(16, 1, 8), 256, 0, stream>>>(zd_acc, 512, b_d, gb_acc, b_f,
                                                     W_o, 1024, out_acc, 1024, 64);
    // 10) e6: + b_o -> out
    e6_kernel<<<(128 * 1024) / 256, 256, 0, stream>>>(out_acc, b_o, out);
}

// Round 4
// 97.367 us; speedup vs baseline: 1.0671x; 1.0671x over previous
//
#include <hip/hip_runtime.h>
#include <math.h>

#define E_DIM 2048

typedef __attribute__((ext_vector_type(8))) short short8;
typedef __attribute__((ext_vector_type(4))) float floatx4;

__device__ __forceinline__ float siluf(float v) { return v / (1.f + expf(-v)); }

// f32 -> bf16 bits, round-to-nearest-even
__device__ __forceinline__ short f2bf(float f) {
    unsigned u = __float_as_uint(f);
    u += 0x7fffu + ((u >> 16) & 1u);
    return (short)(u >> 16);
}

// ---------------- LayerNorm (1024) -> bf16 h ; also convert c -> bf16 ----------------
__global__ __launch_bounds__(256) void ln_cvt_kernel(const float* __restrict__ x,
                                                     const float* __restrict__ g,
                                                     const float* __restrict__ be,
                                                     const float* __restrict__ c,
                                                     short* __restrict__ h_bf,
                                                     short* __restrict__ c_bf) {
    int b = blockIdx.x;
    int tid = threadIdx.x;
    __shared__ float sdata[256];
    const float* xr = x + b * 1024;
    float v[4];
    float s = 0.f;
#pragma unroll
    for (int i = 0; i < 4; ++i) { v[i] = xr[tid + i * 256]; s += v[i]; }
    sdata[tid] = s; __syncthreads();
    for (int st = 128; st > 0; st >>= 1) { if (tid < st) sdata[tid] += sdata[tid + st]; __syncthreads(); }
    float mu = sdata[0] * (1.f / 1024.f);
    __syncthreads();
    float s2 = 0.f;
#pragma unroll
    for (int i = 0; i < 4; ++i) { float d = v[i] - mu; s2 += d * d; }
    sdata[tid] = s2; __syncthreads();
    for (int st = 128; st > 0; st >>= 1) { if (tid < st) sdata[tid] += sdata[tid + st]; __syncthreads(); }
    float var = sdata[0] * (1.f / 1024.f);
    float inv = rsqrtf(var + 1e-5f);
    short* hr = h_bf + b * 1024;
#pragma unroll
    for (int i = 0; i < 4; ++i) {
        int j = tid + i * 256;
        hr[j] = f2bf((v[i] - mu) * inv * g[j] + be[j]);
    }
    const float* cr = c + b * 512;
    short* cbr = c_bf + b * 512;
    for (int j = tid; j < 512; j += 256) cbr[j] = f2bf(cr[j]);
}

// ---------------- MFMA split-K GEMM, NO atomics: each z-block stores its partial slice ----------------
// Block = 4 waves; wave w owns rows [w*32,w*32+32); block owns cols [bx*64, bx*64+64).
// MODE 0: A = bf16 (short*), lda in shorts.
// MODE 3: A = sum of S_A f32 slices of mo (stride 128*1024) + b_out[j] + x[r][j]; lda = 1024.
template<int MODE, int S_A>
__global__ __launch_bounds__(256) void gemm_k(const void* __restrict__ A, int lda,
                                              const float* __restrict__ aux0,
                                              const float* __restrict__ aux1,
                                              const float* __restrict__ B, int ldb,
                                              float* __restrict__ Cp, int ldc,
                                              int kChunk) {
    const int tid = threadIdx.x;
    const int w = tid >> 6;
    const int l = tid & 63;
    const int lane15 = l & 15;
    const int lgrp = l >> 4;
    const int n0 = blockIdx.x * 64;
    const int k0 = blockIdx.z * kChunk;

    const int r0 = w * 32 + lane15;
    const float* Bp = B + (size_t)(k0 + lgrp * 8) * ldb + n0 + lane15;

    floatx4 acc[2][4];
#pragma unroll
    for (int i = 0; i < 2; ++i)
#pragma unroll
        for (int j = 0; j < 4; ++j) acc[i][j] = (floatx4)0.f;

    for (int ks = 0; ks < kChunk; ks += 32) {
        int j0 = k0 + ks + lgrp * 8;
        short8 a0, a1;
        if constexpr (MODE == 0) {
            a0 = *(const short8*)((const short*)A + (size_t)r0 * lda + j0);
            a1 = *(const short8*)((const short*)A + (size_t)(r0 + 16) * lda + j0);
        } else {  // MODE 3: mamba = sum(mo slices) + b_out + x  (add-only fusion)
            const float* Af = (const float*)A;
#pragma unroll
            for (int rr = 0; rr < 2; ++rr) {
                int r = r0 + rr * 16;
                float v[8];
#pragma unroll
                for (int i = 0; i < 8; ++i) {
                    float t = aux0[j0 + i] + aux1[(size_t)r * lda + j0 + i];
#pragma unroll
                    for (int s = 0; s < S_A; ++s)
                        t += Af[(size_t)s * 128 * 1024 + (size_t)r * lda + j0 + i];
                    v[i] = t;
                }
                short8 sv;
#pragma unroll
                for (int i = 0; i < 8; ++i) sv[i] = f2bf(v[i]);
                if (rr == 0) a0 = sv; else a1 = sv;
            }
        }
        float bv[4][8];
#pragma unroll
        for (int i = 0; i < 8; ++i) {
            const float* Br = Bp + i * ldb;
#pragma unroll
            for (int nt = 0; nt < 4; ++nt) bv[nt][i] = Br[nt * 16];
        }
        Bp += 32 * (size_t)ldb;
        short8 vb[4];
#pragma unroll
        for (int nt = 0; nt < 4; ++nt)
#pragma unroll
            for (int i = 0; i < 8; ++i) vb[nt][i] = f2bf(bv[nt][i]);
#pragma unroll
        for (int nt = 0; nt < 4; ++nt) {
            acc[0][nt] = __builtin_amdgcn_mfma_f32_16x16x32_bf16(a0, vb[nt], acc[0][nt], 0, 0, 0);
            acc[1][nt] = __builtin_amdgcn_mfma_f32_16x16x32_bf16(a1, vb[nt], acc[1][nt], 0, 0, 0);
        }
    }
    // plain coalesced store into this z-block's slice
    float* Cs = Cp + (size_t)blockIdx.z * 128 * ldc;
    const int rbase = w * 32 + lgrp * 4;
#pragma unroll
    for (int mf = 0; mf < 2; ++mf)
#pragma unroll
        for (int nt = 0; nt < 4; ++nt)
#pragma unroll
            for (int r = 0; r < 4; ++r)
                Cs[(size_t)(rbase + mf * 16 + r) * ldc + n0 + nt * 16 + lane15] = acc[mf][nt][r];
}

// ---------------- e1: sum 2 xz slices -> u=silu(conv) (f32+bf16), sres=silu(res) ----------------
__global__ __launch_bounds__(256) void e1_kernel(const float* __restrict__ xz_p,
                                                 const float* __restrict__ convw3,
                                                 const float* __restrict__ convb,
                                                 float* __restrict__ u_f32,
                                                 short* __restrict__ u_bf,
                                                 float* __restrict__ sres) {
    int idx = blockIdx.x * 256 + threadIdx.x;  // 128*4096
    int b = idx >> 12, j = idx & 4095;
    float val = xz_p[idx] + xz_p[128 * 4096 + idx];
    if (j < E_DIM) {
        float xc = val * convw3[j] + convb[j];
        float s = siluf(xc);
        u_f32[b * E_DIM + j] = s;
        u_bf[b * E_DIM + j] = f2bf(s);
    } else {
        sres[b * E_DIM + (j - E_DIM)] = siluf(val);
    }
}

// ---------------- svec + dr: sum 8 xdbl slices ----------------
__global__ __launch_bounds__(256) void svec_cvt_kernel(const float* __restrict__ xdbl_p,
                                                       float* __restrict__ svec,
                                                       short* __restrict__ dr_bf) {
    int b = blockIdx.x;
    int tid = threadIdx.x;
    __shared__ float sdata[256];
    const float* row = xdbl_p + (size_t)b * 1536;
    const size_t SL = (size_t)128 * 1536;
    float s = 0.f;
    for (int n = tid; n < 512; n += 256) {
        float bm = 0.f, cm = 0.f;
#pragma unroll
        for (int k = 0; k < 8; ++k) { bm += row[k * SL + 512 + n]; cm += row[k * SL + 1024 + n]; }
        s += bm * cm;
    }
    sdata[tid] = s; __syncthreads();
    for (int st = 128; st > 0; st >>= 1) { if (tid < st) sdata[tid] += sdata[tid + st]; __syncthreads(); }
    if (tid == 0) svec[b] = sdata[0];
    short* dr = dr_bf + b * 512;
    for (int n = tid; n < 512; n += 256) {
        float t = 0.f;
#pragma unroll
        for (int k = 0; k < 8; ++k) t += row[k * SL + n];
        dr[n] = f2bf(t);
    }
}

// ---------------- e3: y = u * (softplus(sum dacc slices + b_dt)*svec + D) * sres -> bf16 ----------------
__global__ __launch_bounds__(256) void e3_kernel(const float* __restrict__ dacc_p,
                                                 const float* __restrict__ b_dt,
                                                 const float* __restrict__ u,
                                                 const float* __restrict__ sres,
                                                 const float* __restrict__ svec,
                                                 const float* __restrict__ Dv,
                                                 short* __restrict__ y_bf) {
    int idx = blockIdx.x * 256 + threadIdx.x;  // 128*2048
    int b = idx >> 11, j = idx & 2047;
    float t = b_dt[j];
#pragma unroll
    for (int s = 0; s < 8; ++s) t += dacc_p[(size_t)s * 128 * 2048 + idx];
    float delta = fmaxf(t, 0.f) + log1pf(expf(-fabsf(t)));  // stable softplus
    y_bf[idx] = f2bf(u[idx] * (delta * svec[b] + Dv[j]) * sres[idx]);
}

// ---------------- e5: z = gelu(sum zd + b_d) * (sum gb + b_f) FiLM -> bf16 ----------------
__global__ __launch_bounds__(256) void e5_kernel(const float* __restrict__ zd_p,
                                                 const float* __restrict__ b_d,
                                                 const float* __restrict__ gb_p,
                                                 const float* __restrict__ b_f,
                                                 short* __restrict__ z_bf) {
    int idx = blockIdx.x * 256 + threadIdx.x;  // 128*512
    int b = idx >> 9, n = idx & 511;
    float t = b_d[n];
#pragma unroll
    for (int s = 0; s < 8; ++s) t += zd_p[(size_t)s * 128 * 512 + idx];
    float zg = 0.5f * t * (1.f + erff(t * 0.70710678118654752f));
    float gq = b_f[n], bb = b_f[512 + n];
#pragma unroll
    for (int s = 0; s < 2; ++s) {
        gq += gb_p[(size_t)s * 128 * 1024 + b * 1024 + n];
        bb += gb_p[(size_t)s * 128 * 1024 + b * 1024 + 512 + n];
    }
    z_bf[idx] = f2bf(zg * gq + bb);
}

// ---------------- e6: out = sum 4 out slices + b_o ----------------
__global__ __launch_bounds__(256) void e6_kernel(const float* __restrict__ out_p,
                                                 const float* __restrict__ b_o,
                                                 float* __restrict__ out) {
    int idx = blockIdx.x * 256 + threadIdx.x;  // 128*1024
    int j = idx & 1023;
    float t = b_o[j];
#pragma unroll
    for (int s = 0; s < 4; ++s) t += out_p[(size_t)s * 128 * 1024 + idx];
    out[idx] = t;
}

extern "C" void kernel_launch(void* const* d_in, const int* in_sizes, int n_in,
                              void* d_out, int out_size, void* d_ws, size_t ws_size,
                              hipStream_t stream) {
    (void)in_sizes; (void)n_in; (void)out_size; (void)ws_size;
    const float* x     = (const float*)d_in[0];
    const float* c     = (const float*)d_in[1];
    const float* ln_g  = (const float*)d_in[2];
    const float* ln_b  = (const float*)d_in[3];
    const float* W_in  = (const float*)d_in[4];
    const float* convw = (const float*)d_in[5];
    const float* convb = (const float*)d_in[6];
    const float* W_x   = (const float*)d_in[7];
    const float* W_dt  = (const float*)d_in[8];
    const float* b_dt  = (const float*)d_in[9];
    // d_in[10] = A_log: provably unused (scan length 1 from h0 = 0)
    const float* Dv    = (const float*)d_in[11];
    const float* W_out = (const float*)d_in[12];
    const float* b_out = (const float*)d_in[13];
    const float* W_d   = (const float*)d_in[14];
    const float* b_d   = (const float*)d_in[15];
    const float* W_f   = (const float*)d_in[16];
    const float* b_f   = (const float*)d_in[17];
    const float* W_o   = (const float*)d_in[18];
    const float* b_o   = (const float*)d_in[19];
    float* out = (float*)d_out;

    char* ws = (char*)d_ws;
    size_t off = 0;
    auto allocf = [&](size_t nElem) { float* p = (float*)(ws + off); off += nElem * sizeof(float); return p; };
    auto allocs = [&](size_t nElem) { short* p = (short*)(ws + off); off += nElem * sizeof(short); return p; };
    // split-K partial slices (plain stores; every element written -> no zeroing needed)
    float* xz_p   = allocf(2 * 128 * 4096);
    float* gb_p   = allocf(2 * 128 * 1024);
    float* xdbl_p = allocf(8 * 128 * 1536);
    float* dacc_p = allocf(8 * 128 * 2048);
    float* mo_p   = allocf(4 * 128 * 1024);
    float* zd_p   = allocf(8 * 128 * 512);
    float* out_p  = allocf(4 * 128 * 1024);
    // activations
    float* u_f32  = allocf(128 * 2048);
    float* sres   = allocf(128 * 2048);
    float* svec   = allocf(128);
    short* h_bf   = allocs(128 * 1024);
    short* c_bf   = allocs(128 * 512);
    short* u_bf   = allocs(128 * 2048);
    short* dr_bf  = allocs(128 * 512);
    short* y_bf   = allocs(128 * 2048);
    short* z_bf   = allocs(128 * 512);

    // 1) LayerNorm + c->bf16
    ln_cvt_kernel<<<128, 256, 0, stream>>>(x, ln_g, ln_b, c, h_bf, c_bf);
    // 2) G1: h @ W_in(1024x4096) -> 2 slices
    gemm_k<0, 0><<<dim3(64, 1, 2), 256, 0, stream>>>(h_bf, 1024, nullptr, nullptr,
                                                     W_in, 4096, xz_p, 4096, 512);
    // 3) G6: c @ W_f(512x1024) -> 2 slices
    gemm_k<0, 0><<<dim3(16, 1, 2), 256, 0, stream>>>(c_bf, 512, nullptr, nullptr,
                                                     W_f, 1024, gb_p, 1024, 256);
    // 4) e1: sum + conv + silu
    e1_kernel<<<(128 * 4096) / 256, 256, 0, stream>>>(xz_p, convw + 3 * E_DIM, convb,
                                                      u_f32, u_bf, sres);
    // 5) G2: u @ W_x(2048x1536) -> 8 slices
    gemm_k<0, 0><<<dim3(24, 1, 8), 256, 0, stream>>>(u_bf, 2048, nullptr, nullptr,
                                                     W_x, 1536, xdbl_p, 1536, 256);
    // 6) svec + dr
    svec_cvt_kernel<<<128, 256, 0, stream>>>(xdbl_p, svec, dr_bf);
    // 7) G3: dr @ W_dt(512x2048) -> 8 slices
    gemm_k<0, 0><<<dim3(32, 1, 8), 256, 0, stream>>>(dr_bf, 512, nullptr, nullptr,
                                                     W_dt, 2048, dacc_p, 2048, 64);
    // 8) e3: y
    e3_kernel<<<(128 * 2048) / 256, 256, 0, stream>>>(dacc_p, b_dt, u_f32, sres, svec, Dv, y_bf);
    // 9) G4: y @ W_out(2048x1024) -> 4 slices
    gemm_k<0, 0><<<dim3(16, 1, 4), 256, 0, stream>>>(y_bf, 2048, nullptr, nullptr,
                                                     W_out, 1024, mo_p, 1024, 512);
    // 10) G5: (sum mo + b_out + x) @ W_d(1024x512) -> 8 slices   [add-only fused loader]
    gemm_k<3, 4><<<dim3(8, 1, 8), 256, 0, stream>>>(mo_p, 1024, b_out, x,
                                                    W_d, 512, zd_p, 512, 128);
    // 11) e5: FiLM(gelu)
    e5_kernel<<<(128 * 512) / 256, 256, 0, stream>>>(zd_p, b_d, gb_p, b_f, z_bf);
    // 12) G7: z @ W_o(512x1024) -> 4 slices
    gemm_k<0, 0><<<dim3(16, 1, 4), 256, 0, stream>>>(z_bf, 512, nullptr, nullptr,
                                                     W_o, 1024, out_p, 1024, 128);
    // 13) e6: final sum + b_o
    e6_kernel<<<(128 * 1024) / 256, 256, 0, stream>>>(out_p, b_o, out);
}